// Round 3
// baseline (642.657 us; speedup 1.0000x reference)
//
#include <hip/hip_runtime.h>
#include <hip/hip_bf16.h>

namespace {
constexpr int Bn = 512;
constexpr int Ln = 1024;
constexpr int Vn = 64;
constexpr int En = 128;
constexpr int Kc = Vn + En;              // 192
constexpr int HP = 136;                  // padded h row (bf16 elems) -> 272B stride
constexpr int WS_FLOATS = En * Kc + En;  // Wall[128][192] + bc[128]
}

typedef __attribute__((ext_vector_type(8))) short bf16x8;
typedef __attribute__((ext_vector_type(4))) float f32x4;

// fp32 -> bf16 bits, round-to-nearest-even
__device__ __forceinline__ unsigned f2b(float f) {
  unsigned u = __float_as_uint(f);
  u += 0x7fffu + ((u >> 16) & 1u);
  return u >> 16;
}
__device__ __forceinline__ float b2f(unsigned short b) {
  return __uint_as_float(((unsigned)b) << 16);
}
__device__ __forceinline__ bf16x8 pack8(const float* v) {
  bf16x8 r;
#pragma unroll
  for (int i = 0; i < 8; ++i) r[i] = (short)f2b(v[i]);
  return r;
}

// Wall[j][k]: k<64 -> sum_e W_in[e][k]*W_h[j][e] (folded input proj); k>=64 -> W_h[j][128+(k-64)]
// bc[j] = b_h[j] + sum_e b_in[e]*W_h[j][e]
__global__ void rnn_setup(const float* __restrict__ W_in, const float* __restrict__ b_in,
                          const float* __restrict__ W_h, const float* __restrict__ b_h,
                          float* __restrict__ ws) {
  const int j = blockIdx.x;    // 0..127
  const int k = threadIdx.x;   // 0..191
  const float* whr = W_h + j * (2 * En);
  float s;
  if (k < Vn) {
    s = 0.f;
#pragma unroll 8
    for (int e = 0; e < En; ++e) s = fmaf(W_in[e * Vn + k], whr[e], s);
  } else {
    s = whr[Vn + k];
  }
  ws[j * Kc + k] = s;
  if (k == 0) {
    float b = b_h[j];
    for (int e = 0; e < En; ++e) b = fmaf(b_in[e], whr[e], b);
    ws[En * Kc + j] = b;
  }
}

__global__ __launch_bounds__(256, 1) void rnn_mfma(
    const float* __restrict__ seq, const float* __restrict__ W_in,
    const float* __restrict__ b_in, const float* __restrict__ W_h,
    const float* __restrict__ b_h, const float* __restrict__ W_out,
    const float* __restrict__ b_out, float* __restrict__ out,
    const float* __restrict__ ws, int use_ws) {
  __shared__ __align__(16) unsigned short hb[2][16][HP];  // h double-buffer, bf16

  const int tid = threadIdx.x;
  const int w   = tid >> 6;   // wave 0..3 -> N cols 32w..32w+31
  const int l   = tid & 63;
  const int l15 = l & 15;     // A row / B,C col within tile
  const int lg  = l >> 4;     // k-group / C row-group
  const int r0  = blockIdx.x * 16;  // batch rows r0..r0+15

  // ---- B-frags (loop-invariant weights) + bias ----
  bf16x8 Bw[2][6];  // [ntile][ktile]
  float bc[2];
  if (use_ws) {
#pragma unroll
    for (int n = 0; n < 2; ++n) {
      const int j = 32 * w + 16 * n + l15;
#pragma unroll
      for (int kt = 0; kt < 6; ++kt) {
        const float* p = ws + j * Kc + kt * 32 + lg * 8;
        float v[8];
#pragma unroll
        for (int i = 0; i < 8; ++i) v[i] = p[i];
        Bw[n][kt] = pack8(v);
      }
      bc[n] = ws[En * Kc + j];
    }
  } else {
#pragma unroll
    for (int n = 0; n < 2; ++n) {
      const int j = 32 * w + 16 * n + l15;
      const float* whr = W_h + j * (2 * En);
      float b = b_h[j];
      for (int e = 0; e < En; ++e) b = fmaf(b_in[e], whr[e], b);
      bc[n] = b;
#pragma unroll
      for (int kt = 0; kt < 6; ++kt) {
        float v[8];
#pragma unroll
        for (int i = 0; i < 8; ++i) {
          const int k = kt * 32 + lg * 8 + i;
          if (k < Vn) {
            float s = 0.f;
            for (int e = 0; e < En; ++e) s = fmaf(W_in[e * Vn + k], whr[e], s);
            v[i] = s;
          } else {
            v[i] = whr[Vn + k];
          }
        }
        Bw[n][kt] = pack8(v);
      }
    }
  }

  // ---- h(0) = 0 ----
  for (int i = tid; i < 2 * 16 * HP; i += 256) ((unsigned short*)hb)[i] = 0;

  // ---- seq per-lane A-frag source: row l15, k-chunk lg*8..+7 (+32 for kt1) ----
  const float* sq = seq + ((size_t)(r0 + l15) * Ln) * Vn + lg * 8;
  f32x4 sA[4], sB[4];  // [0,1]=kt0 (k..k+7), [2,3]=kt1
#define SEQ_PF(dst, T)                                                \
  { const int tp = ((T) < Ln) ? (T) : (Ln - 1);                       \
    const f32x4* p0 = (const f32x4*)(sq + (size_t)tp * Vn);           \
    const f32x4* p1 = (const f32x4*)(sq + (size_t)tp * Vn + 32);      \
    dst[0] = p0[0]; dst[1] = p0[1]; dst[2] = p1[0]; dst[3] = p1[1]; }

  SEQ_PF(sA, 0)
  __syncthreads();  // h init + publishes nothing else; one-time vmcnt drain is fine

#define MFMA __builtin_amdgcn_mfma_f32_16x16x32_bf16

#define STEP(T, SCUR, SNXT)                                                   \
  {                                                                           \
    SEQ_PF(SNXT, (T) + 1);                                                    \
    float v0[8], v1[8];                                                       \
    _Pragma("unroll") for (int i = 0; i < 4; ++i) {                           \
      v0[i] = SCUR[0][i]; v0[4 + i] = SCUR[1][i];                             \
      v1[i] = SCUR[2][i]; v1[4 + i] = SCUR[3][i];                             \
    }                                                                         \
    const bf16x8 a0 = pack8(v0), a1 = pack8(v1);                              \
    f32x4 acc0 = {bc[0], bc[0], bc[0], bc[0]};                                \
    f32x4 acc1 = {bc[1], bc[1], bc[1], bc[1]};                                \
    acc0 = MFMA(a0, Bw[0][0], acc0, 0, 0, 0);                                 \
    acc1 = MFMA(a0, Bw[1][0], acc1, 0, 0, 0);                                 \
    acc0 = MFMA(a1, Bw[0][1], acc0, 0, 0, 0);                                 \
    acc1 = MFMA(a1, Bw[1][1], acc1, 0, 0, 0);                                 \
    const int cb = (T) & 1;                                                   \
    const bf16x8 h0 = *(const bf16x8*)&hb[cb][l15][lg * 8];                   \
    const bf16x8 h1 = *(const bf16x8*)&hb[cb][l15][32 + lg * 8];              \
    const bf16x8 h2 = *(const bf16x8*)&hb[cb][l15][64 + lg * 8];              \
    const bf16x8 h3 = *(const bf16x8*)&hb[cb][l15][96 + lg * 8];              \
    acc0 = MFMA(h0, Bw[0][2], acc0, 0, 0, 0);                                 \
    acc1 = MFMA(h0, Bw[1][2], acc1, 0, 0, 0);                                 \
    acc0 = MFMA(h1, Bw[0][3], acc0, 0, 0, 0);                                 \
    acc1 = MFMA(h1, Bw[1][3], acc1, 0, 0, 0);                                 \
    acc0 = MFMA(h2, Bw[0][4], acc0, 0, 0, 0);                                 \
    acc1 = MFMA(h2, Bw[1][4], acc1, 0, 0, 0);                                 \
    acc0 = MFMA(h3, Bw[0][5], acc0, 0, 0, 0);                                 \
    acc1 = MFMA(h3, Bw[1][5], acc1, 0, 0, 0);                                 \
    const int nb = cb ^ 1;                                                    \
    const int j0 = 32 * w + l15, j1 = j0 + 16, rr = 4 * lg;                   \
    _Pragma("unroll") for (int i = 0; i < 4; ++i) {                           \
      hb[nb][rr + i][j0] = (unsigned short)f2b(fmaxf(acc0[i], 0.f));          \
      hb[nb][rr + i][j1] = (unsigned short)f2b(fmaxf(acc1[i], 0.f));          \
    }                                                                         \
    asm volatile("s_waitcnt lgkmcnt(0)" ::: "memory");                        \
    __builtin_amdgcn_s_barrier();                                             \
    asm volatile("" ::: "memory");                                            \
  }

#pragma unroll 1
  for (int t = 0; t < Ln; t += 2) {
    STEP(t, sA, sB)
    STEP(t + 1, sB, sA)
  }
#undef STEP
#undef SEQ_PF

  // ---- epilogue: out[r0+row][c] = h_final . W_out[c] + b_out[c]; h_final in hb[0] ----
  const int orow = tid >> 4;
  const int oc   = (tid & 15) * 4;
  float o0 = b_out[oc], o1 = b_out[oc + 1], o2 = b_out[oc + 2], o3 = b_out[oc + 3];
  const float* w0 = W_out + (size_t)(oc + 0) * En;
  const float* w1 = W_out + (size_t)(oc + 1) * En;
  const float* w2 = W_out + (size_t)(oc + 2) * En;
  const float* w3 = W_out + (size_t)(oc + 3) * En;
#pragma unroll 8
  for (int k = 0; k < En; ++k) {
    const float hv = b2f(hb[0][orow][k]);
    o0 = fmaf(hv, w0[k], o0);
    o1 = fmaf(hv, w1[k], o1);
    o2 = fmaf(hv, w2[k], o2);
    o3 = fmaf(hv, w3[k], o3);
  }
  *(float4*)&out[(size_t)(r0 + orow) * Vn + oc] = make_float4(o0, o1, o2, o3);
}

extern "C" void kernel_launch(void* const* d_in, const int* in_sizes, int n_in,
                              void* d_out, int out_size, void* d_ws, size_t ws_size,
                              hipStream_t stream) {
  const float* seq   = (const float*)d_in[0];
  const float* W_in  = (const float*)d_in[1];
  const float* b_in  = (const float*)d_in[2];
  const float* W_h   = (const float*)d_in[3];
  const float* b_h   = (const float*)d_in[4];
  const float* W_out = (const float*)d_in[5];
  const float* b_out = (const float*)d_in[6];
  float* out = (float*)d_out;
  float* ws  = (float*)d_ws;

  const int use_ws = (ws_size >= (size_t)WS_FLOATS * sizeof(float)) ? 1 : 0;
  if (use_ws) rnn_setup<<<En, Kc, 0, stream>>>(W_in, b_in, W_h, b_h, ws);
  rnn_mfma<<<Bn / 16, 256, 0, stream>>>(seq, W_in, b_in, W_h, b_h, W_out, b_out,
                                        out, ws, use_ws);
}

// Round 4
// 573.449 us; speedup vs baseline: 1.1207x; 1.1207x over previous
//
#include <hip/hip_runtime.h>
#include <hip/hip_bf16.h>

namespace {
constexpr int Bn = 512;
constexpr int Ln = 1024;
constexpr int Vn = 64;
constexpr int En = 128;
constexpr int Kc = Vn + En;              // 192
constexpr int HP = 136;                  // padded h row (bf16 elems) -> 272B stride
constexpr int WS_FLOATS = En * Kc + En;  // Wall[128][192] + bc[128]
}

typedef __attribute__((ext_vector_type(8))) short bf16x8;
typedef __attribute__((ext_vector_type(4))) float f32x4;

// fp32 -> bf16 bits, round-to-nearest-even
__device__ __forceinline__ unsigned f2b(float f) {
  unsigned u = __float_as_uint(f);
  u += 0x7fffu + ((u >> 16) & 1u);
  return u >> 16;
}
__device__ __forceinline__ float b2f(unsigned short b) {
  return __uint_as_float(((unsigned)b) << 16);
}
__device__ __forceinline__ bf16x8 pack8(const float* v) {
  bf16x8 r;
#pragma unroll
  for (int i = 0; i < 8; ++i) r[i] = (short)f2b(v[i]);
  return r;
}

// Wall[j][k]: k<64 -> sum_e W_in[e][k]*W_h[j][e] (folded input proj); k>=64 -> W_h[j][128+(k-64)]
// bc[j] = b_h[j] + sum_e b_in[e]*W_h[j][e]
__global__ void rnn_setup(const float* __restrict__ W_in, const float* __restrict__ b_in,
                          const float* __restrict__ W_h, const float* __restrict__ b_h,
                          float* __restrict__ ws) {
  const int j = blockIdx.x;    // 0..127
  const int k = threadIdx.x;   // 0..191
  const float* whr = W_h + j * (2 * En);
  float s;
  if (k < Vn) {
    s = 0.f;
#pragma unroll 8
    for (int e = 0; e < En; ++e) s = fmaf(W_in[e * Vn + k], whr[e], s);
  } else {
    s = whr[Vn + k];
  }
  ws[j * Kc + k] = s;
  if (k == 0) {
    float b = b_h[j];
    for (int e = 0; e < En; ++e) b = fmaf(b_in[e], whr[e], b);
    ws[En * Kc + j] = b;
  }
}

__global__ __launch_bounds__(256, 1) void rnn_mfma(
    const float* __restrict__ seq, const float* __restrict__ W_in,
    const float* __restrict__ b_in, const float* __restrict__ W_h,
    const float* __restrict__ b_h, const float* __restrict__ W_out,
    const float* __restrict__ b_out, float* __restrict__ out,
    const float* __restrict__ ws, int use_ws) {
  __shared__ __align__(16) unsigned short hb[2][16][HP];  // h double-buffer, bf16

  const int tid = threadIdx.x;
  const int w   = tid >> 6;   // wave 0..3 -> N cols 32w..32w+31
  const int l   = tid & 63;
  const int l15 = l & 15;     // A row / B,C col within tile
  const int lg  = l >> 4;     // k-group / C row-group
  const int r0  = blockIdx.x * 16;  // batch rows r0..r0+15

  // ---- B-frags (loop-invariant weights) + bias ----
  bf16x8 Bw[2][6];  // [ntile][ktile]
  float bc[2];
  if (use_ws) {
#pragma unroll
    for (int n = 0; n < 2; ++n) {
      const int j = 32 * w + 16 * n + l15;
#pragma unroll
      for (int kt = 0; kt < 6; ++kt) {
        const float* p = ws + j * Kc + kt * 32 + lg * 8;
        float v[8];
#pragma unroll
        for (int i = 0; i < 8; ++i) v[i] = p[i];
        Bw[n][kt] = pack8(v);
      }
      bc[n] = ws[En * Kc + j];
    }
  } else {
#pragma unroll
    for (int n = 0; n < 2; ++n) {
      const int j = 32 * w + 16 * n + l15;
      const float* whr = W_h + j * (2 * En);
      float b = b_h[j];
      for (int e = 0; e < En; ++e) b = fmaf(b_in[e], whr[e], b);
      bc[n] = b;
#pragma unroll
      for (int kt = 0; kt < 6; ++kt) {
        float v[8];
#pragma unroll
        for (int i = 0; i < 8; ++i) {
          const int k = kt * 32 + lg * 8 + i;
          if (k < Vn) {
            float s = 0.f;
            for (int e = 0; e < En; ++e) s = fmaf(W_in[e * Vn + k], whr[e], s);
            v[i] = s;
          } else {
            v[i] = whr[Vn + k];
          }
        }
        Bw[n][kt] = pack8(v);
      }
    }
  }

  // ---- h(0) = 0 ----
  for (int i = tid; i < 2 * 16 * HP; i += 256) ((unsigned short*)hb)[i] = 0;

  // ---- seq per-lane A-frag source: row l15, k-chunks [lg*8, +8) and [32+lg*8, +8) ----
  const float* sq = seq + ((size_t)(r0 + l15) * Ln) * Vn + lg * 8;
  f32x4 sbuf[4][4];  // 4 time-steps deep; [buf][0,1]=k-tile0, [2,3]=k-tile1

#define SEQ_PF(BI, T)                                                 \
  { const int tp = ((T) < Ln) ? (T) : (Ln - 1);                       \
    const f32x4* p0 = (const f32x4*)(sq + (size_t)tp * Vn);           \
    const f32x4* p1 = (const f32x4*)(sq + (size_t)tp * Vn + 32);      \
    sbuf[BI][0] = p0[0]; sbuf[BI][1] = p0[1];                         \
    sbuf[BI][2] = p1[0]; sbuf[BI][3] = p1[1]; }

  SEQ_PF(0, 0)
  SEQ_PF(1, 1)
  SEQ_PF(2, 2)
  __syncthreads();  // h init visible; one-time full drain is fine

#define MFMA __builtin_amdgcn_mfma_f32_16x16x32_bf16

  // Phase(T): [barrier from prev phase guarantees h(T) readable in hb[T&1]]
  //   issue ds_read h(T); issue seq load T+3; pack a(T) + a-MFMAs under LDS latency;
  //   h-MFMAs (depth 2 via accP/accQ); add+relu+cvt; store h(T+1); lgkm-drain + barrier.
#define PHASE(P)                                                              \
  {                                                                           \
    const int T  = t + (P);                                                   \
    const int cb = (P) & 1, nb = cb ^ 1;                                      \
    const bf16x8 h0 = *(const bf16x8*)&hb[cb][l15][lg * 8];                   \
    const bf16x8 h1 = *(const bf16x8*)&hb[cb][l15][32 + lg * 8];              \
    const bf16x8 h2 = *(const bf16x8*)&hb[cb][l15][64 + lg * 8];              \
    const bf16x8 h3 = *(const bf16x8*)&hb[cb][l15][96 + lg * 8];              \
    SEQ_PF(((P) + 3) & 3, T + 3);                                             \
    float v0[8], v1[8];                                                       \
    _Pragma("unroll") for (int i = 0; i < 4; ++i) {                           \
      v0[i] = sbuf[(P)][0][i]; v0[4 + i] = sbuf[(P)][1][i];                   \
      v1[i] = sbuf[(P)][2][i]; v1[4 + i] = sbuf[(P)][3][i];                   \
    }                                                                         \
    const bf16x8 a0 = pack8(v0), a1 = pack8(v1);                              \
    f32x4 p0a = {bc[0], bc[0], bc[0], bc[0]};                                 \
    f32x4 p1a = {bc[1], bc[1], bc[1], bc[1]};                                 \
    f32x4 q0a = {0.f, 0.f, 0.f, 0.f}, q1a = {0.f, 0.f, 0.f, 0.f};             \
    p0a = MFMA(a0, Bw[0][0], p0a, 0, 0, 0);                                   \
    p1a = MFMA(a0, Bw[1][0], p1a, 0, 0, 0);                                   \
    p0a = MFMA(a1, Bw[0][1], p0a, 0, 0, 0);                                   \
    p1a = MFMA(a1, Bw[1][1], p1a, 0, 0, 0);                                   \
    p0a = MFMA(h0, Bw[0][2], p0a, 0, 0, 0);                                   \
    p1a = MFMA(h0, Bw[1][2], p1a, 0, 0, 0);                                   \
    q0a = MFMA(h2, Bw[0][4], q0a, 0, 0, 0);                                   \
    q1a = MFMA(h2, Bw[1][4], q1a, 0, 0, 0);                                   \
    p0a = MFMA(h1, Bw[0][3], p0a, 0, 0, 0);                                   \
    p1a = MFMA(h1, Bw[1][3], p1a, 0, 0, 0);                                   \
    q0a = MFMA(h3, Bw[0][5], q0a, 0, 0, 0);                                   \
    q1a = MFMA(h3, Bw[1][5], q1a, 0, 0, 0);                                   \
    const int j0 = 32 * w + l15, j1 = j0 + 16, rr = 4 * lg;                   \
    _Pragma("unroll") for (int i = 0; i < 4; ++i) {                           \
      hb[nb][rr + i][j0] =                                                    \
          (unsigned short)f2b(fmaxf(p0a[i] + q0a[i], 0.f));                   \
      hb[nb][rr + i][j1] =                                                    \
          (unsigned short)f2b(fmaxf(p1a[i] + q1a[i], 0.f));                   \
    }                                                                         \
    asm volatile("s_waitcnt lgkmcnt(0)" ::: "memory");                        \
    __builtin_amdgcn_s_barrier();                                             \
    asm volatile("" ::: "memory");                                            \
  }

#pragma unroll 1
  for (int t = 0; t < Ln; t += 4) {
    PHASE(0)
    PHASE(1)
    PHASE(2)
    PHASE(3)
  }
#undef PHASE
#undef SEQ_PF

  // ---- epilogue: out[r0+row][c] = h_final . W_out[c] + b_out[c]; h_final in hb[0] ----
  const int orow = tid >> 4;
  const int oc   = (tid & 15) * 4;
  float o0 = b_out[oc], o1 = b_out[oc + 1], o2 = b_out[oc + 2], o3 = b_out[oc + 3];
  const float* w0 = W_out + (size_t)(oc + 0) * En;
  const float* w1 = W_out + (size_t)(oc + 1) * En;
  const float* w2 = W_out + (size_t)(oc + 2) * En;
  const float* w3 = W_out + (size_t)(oc + 3) * En;
#pragma unroll 8
  for (int k = 0; k < En; ++k) {
    const float hv = b2f(hb[0][orow][k]);
    o0 = fmaf(hv, w0[k], o0);
    o1 = fmaf(hv, w1[k], o1);
    o2 = fmaf(hv, w2[k], o2);
    o3 = fmaf(hv, w3[k], o3);
  }
  *(float4*)&out[(size_t)(r0 + orow) * Vn + oc] = make_float4(o0, o1, o2, o3);
}

extern "C" void kernel_launch(void* const* d_in, const int* in_sizes, int n_in,
                              void* d_out, int out_size, void* d_ws, size_t ws_size,
                              hipStream_t stream) {
  const float* seq   = (const float*)d_in[0];
  const float* W_in  = (const float*)d_in[1];
  const float* b_in  = (const float*)d_in[2];
  const float* W_h   = (const float*)d_in[3];
  const float* b_h   = (const float*)d_in[4];
  const float* W_out = (const float*)d_in[5];
  const float* b_out = (const float*)d_in[6];
  float* out = (float*)d_out;
  float* ws  = (float*)d_ws;

  const int use_ws = (ws_size >= (size_t)WS_FLOATS * sizeof(float)) ? 1 : 0;
  if (use_ws) rnn_setup<<<En, Kc, 0, stream>>>(W_in, b_in, W_h, b_h, ws);
  rnn_mfma<<<Bn / 16, 256, 0, stream>>>(seq, W_in, b_in, W_h, b_h, W_out, b_out,
                                        out, ws, use_ws);
}

// Round 5
// 502.343 us; speedup vs baseline: 1.2793x; 1.1415x over previous
//
#include <hip/hip_runtime.h>
#include <hip/hip_bf16.h>

namespace {
constexpr int Bn = 512;
constexpr int Ln = 1024;
constexpr int Vn = 64;
constexpr int En = 128;
constexpr int Kc = Vn + En;              // 192
constexpr int HP = 136;                  // padded h row (bf16 elems) -> 272B stride
constexpr int WS_FLOATS = En * Kc + En;  // fallback: Wall[128][192] + bc[128] (fp32)
constexpr size_t SEQB_BYTES = (size_t)Bn * Ln * Vn * 2;  // 67,108,864
constexpr size_t WALLB_BYTES = (size_t)En * Kc * 2;      // 49,152
constexpr size_t FAST_WS = SEQB_BYTES + WALLB_BYTES + En * 4;
}

typedef __attribute__((ext_vector_type(8))) short bf16x8;
typedef __attribute__((ext_vector_type(4))) float f32x4;
typedef __attribute__((ext_vector_type(8))) unsigned short u16x8;

// fp32 -> bf16 bits, round-to-nearest-even
__device__ __forceinline__ unsigned f2b(float f) {
  unsigned u = __float_as_uint(f);
  u += 0x7fffu + ((u >> 16) & 1u);
  return u >> 16;
}
__device__ __forceinline__ float b2f(unsigned short b) {
  return __uint_as_float(((unsigned)b) << 16);
}
__device__ __forceinline__ bf16x8 pack8(const float* v) {
  bf16x8 r;
#pragma unroll
  for (int i = 0; i < 8; ++i) r[i] = (short)f2b(v[i]);
  return r;
}

// ---------------- fast path ----------------

// seq fp32 -> bf16 (bulk, memory-bound)
__global__ void seq_cvt(const float* __restrict__ seq, unsigned short* __restrict__ seqb) {
  const size_t n = (size_t)Bn * Ln * Vn;
  size_t i = ((size_t)blockIdx.x * blockDim.x + threadIdx.x) * 8;
  const size_t stride = (size_t)gridDim.x * blockDim.x * 8;
  for (; i < n; i += stride) {
    const f32x4 a = *(const f32x4*)(seq + i);
    const f32x4 b = *(const f32x4*)(seq + i + 4);
    u16x8 o;
#pragma unroll
    for (int j = 0; j < 4; ++j) o[j] = (unsigned short)f2b(a[j]);
#pragma unroll
    for (int j = 0; j < 4; ++j) o[4 + j] = (unsigned short)f2b(b[j]);
    *(u16x8*)(seqb + i) = o;
  }
}

// Wall[j][k] (bf16): k<64 -> sum_e W_in[e][k]*W_h[j][e]; k>=64 -> W_h[j][128+(k-64)]
// bc[j] (f32) = b_h[j] + sum_e b_in[e]*W_h[j][e]
__global__ void rnn_setup_bf(const float* __restrict__ W_in, const float* __restrict__ b_in,
                             const float* __restrict__ W_h, const float* __restrict__ b_h,
                             unsigned short* __restrict__ wallb, float* __restrict__ bc) {
  const int j = blockIdx.x;    // 0..127
  const int k = threadIdx.x;   // 0..191
  const float* whr = W_h + j * (2 * En);
  float s;
  if (k < Vn) {
    s = 0.f;
#pragma unroll 8
    for (int e = 0; e < En; ++e) s = fmaf(W_in[e * Vn + k], whr[e], s);
  } else {
    s = whr[Vn + k];
  }
  wallb[j * Kc + k] = (unsigned short)f2b(s);
  if (k == 0) {
    float b = b_h[j];
    for (int e = 0; e < En; ++e) b = fmaf(b_in[e], whr[e], b);
    bc[j] = b;
  }
}

// 8 waves; wave w owns output cols [16w,16w+16). A = weight tile, B = z tile.
// D: col=l15=batch row, row=4*lg+i = j-within-tile -> lane's 4 outputs are 4
// consecutive h elems -> 2x cvt_pk + one ds_write_b64.
__global__ __launch_bounds__(512, 1) void rnn_fast(
    const unsigned short* __restrict__ seqb, const unsigned short* __restrict__ wallb,
    const float* __restrict__ bc, const float* __restrict__ W_out,
    const float* __restrict__ b_out, float* __restrict__ out) {
  __shared__ __align__(16) unsigned short hb[2][16][HP];

  const int tid = threadIdx.x;
  const int w   = tid >> 6;   // 0..7
  const int l   = tid & 63;
  const int l15 = l & 15;
  const int lg  = l >> 4;
  const int r0  = blockIdx.x * 16;

  // A-frags (weights): lane holds Wall[16w+l15][kt*32 + lg*8 .. +7]
  bf16x8 Bw[6];
  {
    const unsigned short* p = wallb + (16 * w + l15) * Kc + lg * 8;
#pragma unroll
    for (int kt = 0; kt < 6; ++kt) Bw[kt] = *(const bf16x8*)(p + kt * 32);
  }
  const f32x4 bcv4 = *(const f32x4*)(bc + 16 * w + 4 * lg);  // bias for j = 16w+4lg+i

  // h(0) = 0
  for (int i = tid; i < 2 * 16 * HP; i += 512) ((unsigned short*)hb)[i] = 0;

  // seq source: batch row l15, k-chunk lg*8 (kt0) / 32+lg*8 (kt1); bf16, 16B loads
  const unsigned short* sqb = seqb + ((size_t)(r0 + l15) * Ln) * Vn + lg * 8;
  bf16x8 sreg[4][2];

#define SEQ_PF(BI, T)                                                \
  { const int tp = ((T) < Ln) ? (T) : (Ln - 1);                      \
    const bf16x8* sp = (const bf16x8*)(sqb + (size_t)tp * Vn);       \
    sreg[BI][0] = sp[0];                                             \
    sreg[BI][1] = sp[4]; }

  SEQ_PF(0, 0)
  SEQ_PF(1, 1)
  SEQ_PF(2, 2)
  __syncthreads();

#define MFMA __builtin_amdgcn_mfma_f32_16x16x32_bf16

#define PHASE(P)                                                              \
  {                                                                           \
    const int T  = t + (P);                                                   \
    const int cb = (P) & 1, nb = cb ^ 1;                                      \
    const bf16x8 z0 = *(const bf16x8*)&hb[cb][l15][lg * 8];                   \
    const bf16x8 z1 = *(const bf16x8*)&hb[cb][l15][32 + lg * 8];              \
    const bf16x8 z2 = *(const bf16x8*)&hb[cb][l15][64 + lg * 8];              \
    const bf16x8 z3 = *(const bf16x8*)&hb[cb][l15][96 + lg * 8];              \
    SEQ_PF(((P) + 3) & 3, T + 3);                                             \
    f32x4 accP = bcv4;                                                        \
    f32x4 accQ = {0.f, 0.f, 0.f, 0.f};                                        \
    accP = MFMA(Bw[0], sreg[(P)][0], accP, 0, 0, 0);                          \
    accQ = MFMA(Bw[1], sreg[(P)][1], accQ, 0, 0, 0);                          \
    accP = MFMA(Bw[2], z0, accP, 0, 0, 0);                                    \
    accQ = MFMA(Bw[3], z1, accQ, 0, 0, 0);                                    \
    accP = MFMA(Bw[4], z2, accP, 0, 0, 0);                                    \
    accQ = MFMA(Bw[5], z3, accQ, 0, 0, 0);                                    \
    const float r0v = fmaxf(accP[0] + accQ[0], 0.f);                          \
    const float r1v = fmaxf(accP[1] + accQ[1], 0.f);                          \
    const float r2v = fmaxf(accP[2] + accQ[2], 0.f);                          \
    const float r3v = fmaxf(accP[3] + accQ[3], 0.f);                          \
    unsigned d0, d1;                                                          \
    asm("v_cvt_pk_bf16_f32 %0, %1, %2" : "=v"(d0) : "v"(r0v), "v"(r1v));      \
    asm("v_cvt_pk_bf16_f32 %0, %1, %2" : "=v"(d1) : "v"(r2v), "v"(r3v));      \
    uint2 dd; dd.x = d0; dd.y = d1;                                           \
    *(uint2*)&hb[nb][l15][16 * w + 4 * lg] = dd;                              \
    asm volatile("s_waitcnt lgkmcnt(0)" ::: "memory");                        \
    __builtin_amdgcn_s_barrier();                                             \
    asm volatile("" ::: "memory");                                            \
  }

#pragma unroll 1
  for (int t = 0; t < Ln; t += 4) {
    PHASE(0)
    PHASE(1)
    PHASE(2)
    PHASE(3)
  }
#undef PHASE
#undef SEQ_PF

  // epilogue: h_final in hb[0]
  if (tid < 256) {
    const int orow = tid >> 4;
    const int oc   = (tid & 15) * 4;
    float o0 = b_out[oc], o1 = b_out[oc + 1], o2 = b_out[oc + 2], o3 = b_out[oc + 3];
    const float* w0 = W_out + (size_t)(oc + 0) * En;
    const float* w1 = W_out + (size_t)(oc + 1) * En;
    const float* w2 = W_out + (size_t)(oc + 2) * En;
    const float* w3 = W_out + (size_t)(oc + 3) * En;
#pragma unroll 8
    for (int k = 0; k < En; ++k) {
      const float hv = b2f(hb[0][orow][k]);
      o0 = fmaf(hv, w0[k], o0);
      o1 = fmaf(hv, w1[k], o1);
      o2 = fmaf(hv, w2[k], o2);
      o3 = fmaf(hv, w3[k], o3);
    }
    *(float4*)&out[(size_t)(r0 + orow) * Vn + oc] = make_float4(o0, o1, o2, o3);
  }
}

// ---------------- fallback path (round-4 kernel, known-correct) ----------------

__global__ void rnn_setup(const float* __restrict__ W_in, const float* __restrict__ b_in,
                          const float* __restrict__ W_h, const float* __restrict__ b_h,
                          float* __restrict__ ws) {
  const int j = blockIdx.x;
  const int k = threadIdx.x;
  const float* whr = W_h + j * (2 * En);
  float s;
  if (k < Vn) {
    s = 0.f;
#pragma unroll 8
    for (int e = 0; e < En; ++e) s = fmaf(W_in[e * Vn + k], whr[e], s);
  } else {
    s = whr[Vn + k];
  }
  ws[j * Kc + k] = s;
  if (k == 0) {
    float b = b_h[j];
    for (int e = 0; e < En; ++e) b = fmaf(b_in[e], whr[e], b);
    ws[En * Kc + j] = b;
  }
}

__global__ __launch_bounds__(256, 1) void rnn_mfma(
    const float* __restrict__ seq, const float* __restrict__ W_in,
    const float* __restrict__ b_in, const float* __restrict__ W_h,
    const float* __restrict__ b_h, const float* __restrict__ W_out,
    const float* __restrict__ b_out, float* __restrict__ out,
    const float* __restrict__ ws, int use_ws) {
  __shared__ __align__(16) unsigned short hb[2][16][HP];

  const int tid = threadIdx.x;
  const int w   = tid >> 6;
  const int l   = tid & 63;
  const int l15 = l & 15;
  const int lg  = l >> 4;
  const int r0  = blockIdx.x * 16;

  bf16x8 Bw[2][6];
  float bc[2];
  if (use_ws) {
#pragma unroll
    for (int n = 0; n < 2; ++n) {
      const int j = 32 * w + 16 * n + l15;
#pragma unroll
      for (int kt = 0; kt < 6; ++kt) {
        const float* p = ws + j * Kc + kt * 32 + lg * 8;
        float v[8];
#pragma unroll
        for (int i = 0; i < 8; ++i) v[i] = p[i];
        Bw[n][kt] = pack8(v);
      }
      bc[n] = ws[En * Kc + j];
    }
  } else {
#pragma unroll
    for (int n = 0; n < 2; ++n) {
      const int j = 32 * w + 16 * n + l15;
      const float* whr = W_h + j * (2 * En);
      float b = b_h[j];
      for (int e = 0; e < En; ++e) b = fmaf(b_in[e], whr[e], b);
      bc[n] = b;
#pragma unroll
      for (int kt = 0; kt < 6; ++kt) {
        float v[8];
#pragma unroll
        for (int i = 0; i < 8; ++i) {
          const int k = kt * 32 + lg * 8 + i;
          if (k < Vn) {
            float s = 0.f;
            for (int e = 0; e < En; ++e) s = fmaf(W_in[e * Vn + k], whr[e], s);
            v[i] = s;
          } else {
            v[i] = whr[Vn + k];
          }
        }
        Bw[n][kt] = pack8(v);
      }
    }
  }

  for (int i = tid; i < 2 * 16 * HP; i += 256) ((unsigned short*)hb)[i] = 0;

  const float* sq = seq + ((size_t)(r0 + l15) * Ln) * Vn + lg * 8;
  f32x4 sbuf[4][4];

#define SEQ_PF(BI, T)                                                 \
  { const int tp = ((T) < Ln) ? (T) : (Ln - 1);                       \
    const f32x4* p0 = (const f32x4*)(sq + (size_t)tp * Vn);           \
    const f32x4* p1 = (const f32x4*)(sq + (size_t)tp * Vn + 32);      \
    sbuf[BI][0] = p0[0]; sbuf[BI][1] = p0[1];                         \
    sbuf[BI][2] = p1[0]; sbuf[BI][3] = p1[1]; }

  SEQ_PF(0, 0)
  SEQ_PF(1, 1)
  SEQ_PF(2, 2)
  __syncthreads();

#define PHASE(P)                                                              \
  {                                                                           \
    const int T  = t + (P);                                                   \
    const int cb = (P) & 1, nb = cb ^ 1;                                      \
    const bf16x8 h0 = *(const bf16x8*)&hb[cb][l15][lg * 8];                   \
    const bf16x8 h1 = *(const bf16x8*)&hb[cb][l15][32 + lg * 8];              \
    const bf16x8 h2 = *(const bf16x8*)&hb[cb][l15][64 + lg * 8];              \
    const bf16x8 h3 = *(const bf16x8*)&hb[cb][l15][96 + lg * 8];              \
    SEQ_PF(((P) + 3) & 3, T + 3);                                             \
    float v0[8], v1[8];                                                       \
    _Pragma("unroll") for (int i = 0; i < 4; ++i) {                           \
      v0[i] = sbuf[(P)][0][i]; v0[4 + i] = sbuf[(P)][1][i];                   \
      v1[i] = sbuf[(P)][2][i]; v1[4 + i] = sbuf[(P)][3][i];                   \
    }                                                                         \
    const bf16x8 a0 = pack8(v0), a1 = pack8(v1);                              \
    f32x4 p0a = {bc[0], bc[0], bc[0], bc[0]};                                 \
    f32x4 p1a = {bc[1], bc[1], bc[1], bc[1]};                                 \
    f32x4 q0a = {0.f, 0.f, 0.f, 0.f}, q1a = {0.f, 0.f, 0.f, 0.f};             \
    p0a = __builtin_amdgcn_mfma_f32_16x16x32_bf16(a0, Bw[0][0], p0a, 0, 0, 0);\
    p1a = __builtin_amdgcn_mfma_f32_16x16x32_bf16(a0, Bw[1][0], p1a, 0, 0, 0);\
    p0a = __builtin_amdgcn_mfma_f32_16x16x32_bf16(a1, Bw[0][1], p0a, 0, 0, 0);\
    p1a = __builtin_amdgcn_mfma_f32_16x16x32_bf16(a1, Bw[1][1], p1a, 0, 0, 0);\
    p0a = __builtin_amdgcn_mfma_f32_16x16x32_bf16(h0, Bw[0][2], p0a, 0, 0, 0);\
    p1a = __builtin_amdgcn_mfma_f32_16x16x32_bf16(h0, Bw[1][2], p1a, 0, 0, 0);\
    q0a = __builtin_amdgcn_mfma_f32_16x16x32_bf16(h2, Bw[0][4], q0a, 0, 0, 0);\
    q1a = __builtin_amdgcn_mfma_f32_16x16x32_bf16(h2, Bw[1][4], q1a, 0, 0, 0);\
    p0a = __builtin_amdgcn_mfma_f32_16x16x32_bf16(h1, Bw[0][3], p0a, 0, 0, 0);\
    p1a = __builtin_amdgcn_mfma_f32_16x16x32_bf16(h1, Bw[1][3], p1a, 0, 0, 0);\
    q0a = __builtin_amdgcn_mfma_f32_16x16x32_bf16(h3, Bw[0][5], q0a, 0, 0, 0);\
    q1a = __builtin_amdgcn_mfma_f32_16x16x32_bf16(h3, Bw[1][5], q1a, 0, 0, 0);\
    const int j0 = 32 * w + l15, j1 = j0 + 16, rr = 4 * lg;                   \
    _Pragma("unroll") for (int i = 0; i < 4; ++i) {                           \
      hb[nb][rr + i][j0] = (unsigned short)f2b(fmaxf(p0a[i] + q0a[i], 0.f));  \
      hb[nb][rr + i][j1] = (unsigned short)f2b(fmaxf(p1a[i] + q1a[i], 0.f));  \
    }                                                                         \
    asm volatile("s_waitcnt lgkmcnt(0)" ::: "memory");                        \
    __builtin_amdgcn_s_barrier();                                             \
    asm volatile("" ::: "memory");                                            \
  }

#pragma unroll 1
  for (int t = 0; t < Ln; t += 4) {
    PHASE(0)
    PHASE(1)
    PHASE(2)
    PHASE(3)
  }
#undef PHASE
#undef SEQ_PF

  const int orow = tid >> 4;
  const int oc   = (tid & 15) * 4;
  float o0 = b_out[oc], o1 = b_out[oc + 1], o2 = b_out[oc + 2], o3 = b_out[oc + 3];
  const float* w0 = W_out + (size_t)(oc + 0) * En;
  const float* w1 = W_out + (size_t)(oc + 1) * En;
  const float* w2 = W_out + (size_t)(oc + 2) * En;
  const float* w3 = W_out + (size_t)(oc + 3) * En;
#pragma unroll 8
  for (int k = 0; k < En; ++k) {
    const float hv = b2f(hb[0][orow][k]);
    o0 = fmaf(hv, w0[k], o0);
    o1 = fmaf(hv, w1[k], o1);
    o2 = fmaf(hv, w2[k], o2);
    o3 = fmaf(hv, w3[k], o3);
  }
  *(float4*)&out[(size_t)(r0 + orow) * Vn + oc] = make_float4(o0, o1, o2, o3);
}

extern "C" void kernel_launch(void* const* d_in, const int* in_sizes, int n_in,
                              void* d_out, int out_size, void* d_ws, size_t ws_size,
                              hipStream_t stream) {
  const float* seq   = (const float*)d_in[0];
  const float* W_in  = (const float*)d_in[1];
  const float* b_in  = (const float*)d_in[2];
  const float* W_h   = (const float*)d_in[3];
  const float* b_h   = (const float*)d_in[4];
  const float* W_out = (const float*)d_in[5];
  const float* b_out = (const float*)d_in[6];
  float* out = (float*)d_out;

  if (ws_size >= FAST_WS) {
    unsigned short* seqb  = (unsigned short*)d_ws;
    unsigned short* wallb = (unsigned short*)((char*)d_ws + SEQB_BYTES);
    float* bc = (float*)((char*)d_ws + SEQB_BYTES + WALLB_BYTES);
    seq_cvt<<<2048, 256, 0, stream>>>(seq, seqb);
    rnn_setup_bf<<<En, Kc, 0, stream>>>(W_in, b_in, W_h, b_h, wallb, bc);
    rnn_fast<<<Bn / 16, 512, 0, stream>>>(seqb, wallb, bc, W_out, b_out, out);
  } else if (ws_size >= (size_t)WS_FLOATS * sizeof(float)) {
    float* ws = (float*)d_ws;
    rnn_setup<<<En, Kc, 0, stream>>>(W_in, b_in, W_h, b_h, ws);
    rnn_mfma<<<Bn / 16, 256, 0, stream>>>(seq, W_in, b_in, W_h, b_h, W_out, b_out,
                                          out, ws, 1);
  } else {
    rnn_mfma<<<Bn / 16, 256, 0, stream>>>(seq, W_in, b_in, W_h, b_h, W_out, b_out,
                                          out, (const float*)nullptr, 0);
  }
}

// Round 6
// 405.701 us; speedup vs baseline: 1.5841x; 1.2382x over previous
//
#include <hip/hip_runtime.h>
#include <hip/hip_bf16.h>

namespace {
constexpr int Bn = 512;
constexpr int Ln = 1024;
constexpr int Vn = 64;
constexpr int En = 128;
constexpr int Kc = Vn + En;              // 192
constexpr int HP = 136;                  // fallback kernel only
constexpr int WS_FLOATS = En * Kc + En;  // fallback: Wall fp32 + bc
constexpr size_t SEQB_BYTES = (size_t)Bn * Ln * Vn * 2;  // 67,108,864
constexpr size_t WALLB_BYTES = (size_t)En * Kc * 2;      // 49,152
constexpr size_t FAST_WS = SEQB_BYTES + WALLB_BYTES + En * 4;
}

typedef __attribute__((ext_vector_type(8))) short bf16x8;
typedef __attribute__((ext_vector_type(4))) float f32x4;
typedef __attribute__((ext_vector_type(8))) unsigned short u16x8;

__device__ __forceinline__ unsigned f2b(float f) {
  unsigned u = __float_as_uint(f);
  u += 0x7fffu + ((u >> 16) & 1u);
  return u >> 16;
}
__device__ __forceinline__ float b2f(unsigned short b) {
  return __uint_as_float(((unsigned)b) << 16);
}
__device__ __forceinline__ bf16x8 pack8(const float* v) {
  bf16x8 r;
#pragma unroll
  for (int i = 0; i < 8; ++i) r[i] = (short)f2b(v[i]);
  return r;
}

#define MFMA __builtin_amdgcn_mfma_f32_16x16x32_bf16

// ---------------- fast path ----------------

// seq fp32 -> bf16 (bulk, memory-bound)
__global__ void seq_cvt(const float* __restrict__ seq, unsigned short* __restrict__ seqb) {
  const size_t n = (size_t)Bn * Ln * Vn;
  size_t i = ((size_t)blockIdx.x * blockDim.x + threadIdx.x) * 8;
  const size_t stride = (size_t)gridDim.x * blockDim.x * 8;
  for (; i < n; i += stride) {
    const f32x4 a = *(const f32x4*)(seq + i);
    const f32x4 b = *(const f32x4*)(seq + i + 4);
    u16x8 o;
#pragma unroll
    for (int j = 0; j < 4; ++j) o[j] = (unsigned short)f2b(a[j]);
#pragma unroll
    for (int j = 0; j < 4; ++j) o[4 + j] = (unsigned short)f2b(b[j]);
    *(u16x8*)(seqb + i) = o;
  }
}

// Wall[j][k] (bf16): k<64 -> sum_e W_in[e][k]*W_h[j][e]; k>=64 -> W_h[j][128+(k-64)]
// bc[j] (f32) = b_h[j] + sum_e b_in[e]*W_h[j][e]
__global__ void rnn_setup_bf(const float* __restrict__ W_in, const float* __restrict__ b_in,
                             const float* __restrict__ W_h, const float* __restrict__ b_h,
                             unsigned short* __restrict__ wallb, float* __restrict__ bc) {
  const int j = blockIdx.x;    // 0..127
  const int k = threadIdx.x;   // 0..191
  const float* whr = W_h + j * (2 * En);
  float s;
  if (k < Vn) {
    s = 0.f;
#pragma unroll 8
    for (int e = 0; e < En; ++e) s = fmaf(W_in[e * Vn + k], whr[e], s);
  } else {
    s = whr[Vn + k];
  }
  wallb[j * Kc + k] = (unsigned short)f2b(s);
  if (k == 0) {
    float b = b_h[j];
    for (int e = 0; e < En; ++e) b = fmaf(b_in[e], whr[e], b);
    bc[j] = b;
  }
}

// 2 waves / 128 threads. Wave w owns n-tiles 4w..4w+3 (output cols j = 64w..64w+63).
// z (h-part) lives in a 2-buffer XOR-swizzled LDS layout: [batch row: 256B][j],
// byte-in-row ^= (batch&7)<<4. Writes: ds_write_b64 per tile; reads: 4x b128.
__global__ __launch_bounds__(128, 1) void rnn_fast2(
    const unsigned short* __restrict__ seqb, const unsigned short* __restrict__ wallb,
    const float* __restrict__ bc, const float* __restrict__ W_out,
    const float* __restrict__ b_out, float* __restrict__ out) {
  __shared__ __align__(16) unsigned char hbB[2][4096];

  const int tid = threadIdx.x;
  const int w   = tid >> 6;   // 0..1
  const int l   = tid & 63;
  const int l15 = l & 15;     // batch row within tile / B,C col
  const int lg  = l >> 4;     // k-group / C row-group
  const int r0  = blockIdx.x * 16;
  const int swz = (l15 & 7) << 4;

  // A-frags (weights, loop-invariant): Aw[nn][kt] = Wall[16(4w+nn)+l15][32kt+8lg..+7]
  bf16x8 Aw[4][6];
  f32x4 bcv[4];
#pragma unroll
  for (int nn = 0; nn < 4; ++nn) {
    const int n = 4 * w + nn;
    const unsigned short* p = wallb + (size_t)(16 * n + l15) * Kc + lg * 8;
#pragma unroll
    for (int kt = 0; kt < 6; ++kt) Aw[nn][kt] = *(const bf16x8*)(p + kt * 32);
    bcv[nn] = *(const f32x4*)(bc + 16 * n + 4 * lg);
  }

  // h(0) = 0 (both buffers)
  for (int i = tid; i < 2048; i += 128) ((unsigned int*)hbB)[i] = 0u;

  // seq source: batch row r0+l15, k-chunk lg*8 (kt0) / 32+lg*8 (kt1)
  const unsigned short* sqb = seqb + ((size_t)(r0 + l15) * Ln) * Vn + lg * 8;
  bf16x8 sreg[4][2];

#define SEQ_PF(BI, T)                                                \
  { const int tp = ((T) < Ln) ? (T) : (Ln - 1);                      \
    const bf16x8* sp = (const bf16x8*)(sqb + (size_t)tp * Vn);       \
    sreg[BI][0] = sp[0];                                             \
    sreg[BI][1] = sp[4]; }

  SEQ_PF(0, 0)
  SEQ_PF(1, 1)
  SEQ_PF(2, 2)
  __syncthreads();

  // Per phase: read z(T) (4x swizzled b128), prefetch seq T+3, 8 seq-MFMAs
  // (independent, hide LDS latency), 16 h-MFMAs (P/Q chains of 3), relu+cvt,
  // 4x ds_write_b64 into buffer T+1, lgkm-drain, barrier.
#define PHASE(P)                                                               \
  {                                                                            \
    const int cb = (P) & 1;                                                    \
    const unsigned char* zb = hbB[cb] + l15 * 256;                             \
    const bf16x8 z0 = *(const bf16x8*)(zb + ((16 * lg) ^ swz));                \
    const bf16x8 z1 = *(const bf16x8*)(zb + ((64 + 16 * lg) ^ swz));           \
    const bf16x8 z2 = *(const bf16x8*)(zb + ((128 + 16 * lg) ^ swz));          \
    const bf16x8 z3 = *(const bf16x8*)(zb + ((192 + 16 * lg) ^ swz));          \
    SEQ_PF(((P) + 3) & 3, t + (P) + 3);                                        \
    const bf16x8 s0 = sreg[(P)][0], s1 = sreg[(P)][1];                         \
    f32x4 p0 = bcv[0], p1 = bcv[1], p2 = bcv[2], p3 = bcv[3];                  \
    f32x4 q0 = {0.f, 0.f, 0.f, 0.f}, q1 = {0.f, 0.f, 0.f, 0.f};                \
    f32x4 q2 = {0.f, 0.f, 0.f, 0.f}, q3 = {0.f, 0.f, 0.f, 0.f};                \
    p0 = MFMA(Aw[0][0], s0, p0, 0, 0, 0);                                      \
    p1 = MFMA(Aw[1][0], s0, p1, 0, 0, 0);                                      \
    p2 = MFMA(Aw[2][0], s0, p2, 0, 0, 0);                                      \
    p3 = MFMA(Aw[3][0], s0, p3, 0, 0, 0);                                      \
    q0 = MFMA(Aw[0][1], s1, q0, 0, 0, 0);                                      \
    q1 = MFMA(Aw[1][1], s1, q1, 0, 0, 0);                                      \
    q2 = MFMA(Aw[2][1], s1, q2, 0, 0, 0);                                      \
    q3 = MFMA(Aw[3][1], s1, q3, 0, 0, 0);                                      \
    p0 = MFMA(Aw[0][2], z0, p0, 0, 0, 0);                                      \
    p1 = MFMA(Aw[1][2], z0, p1, 0, 0, 0);                                      \
    p2 = MFMA(Aw[2][2], z0, p2, 0, 0, 0);                                      \
    p3 = MFMA(Aw[3][2], z0, p3, 0, 0, 0);                                      \
    q0 = MFMA(Aw[0][3], z1, q0, 0, 0, 0);                                      \
    q1 = MFMA(Aw[1][3], z1, q1, 0, 0, 0);                                      \
    q2 = MFMA(Aw[2][3], z1, q2, 0, 0, 0);                                      \
    q3 = MFMA(Aw[3][3], z1, q3, 0, 0, 0);                                      \
    p0 = MFMA(Aw[0][4], z2, p0, 0, 0, 0);                                      \
    p1 = MFMA(Aw[1][4], z2, p1, 0, 0, 0);                                      \
    p2 = MFMA(Aw[2][4], z2, p2, 0, 0, 0);                                      \
    p3 = MFMA(Aw[3][4], z2, p3, 0, 0, 0);                                      \
    q0 = MFMA(Aw[0][5], z3, q0, 0, 0, 0);                                      \
    q1 = MFMA(Aw[1][5], z3, q1, 0, 0, 0);                                      \
    q2 = MFMA(Aw[2][5], z3, q2, 0, 0, 0);                                      \
    q3 = MFMA(Aw[3][5], z3, q3, 0, 0, 0);                                      \
    unsigned char* wbB = hbB[cb ^ 1] + l15 * 256;                              \
    _Pragma("unroll") for (int nn = 0; nn < 4; ++nn) {                         \
      const f32x4 pp = (nn == 0) ? p0 : (nn == 1) ? p1 : (nn == 2) ? p2 : p3;  \
      const f32x4 qq = (nn == 0) ? q0 : (nn == 1) ? q1 : (nn == 2) ? q2 : q3;  \
      const float r0v = fmaxf(pp[0] + qq[0], 0.f);                             \
      const float r1v = fmaxf(pp[1] + qq[1], 0.f);                             \
      const float r2v = fmaxf(pp[2] + qq[2], 0.f);                             \
      const float r3v = fmaxf(pp[3] + qq[3], 0.f);                             \
      unsigned d0, d1;                                                         \
      asm("v_cvt_pk_bf16_f32 %0, %1, %2" : "=v"(d0) : "v"(r0v), "v"(r1v));     \
      asm("v_cvt_pk_bf16_f32 %0, %1, %2" : "=v"(d1) : "v"(r2v), "v"(r3v));     \
      uint2 dd; dd.x = d0; dd.y = d1;                                          \
      *(uint2*)(wbB + ((128 * w + 32 * nn + 8 * lg) ^ swz)) = dd;              \
    }                                                                          \
    asm volatile("s_waitcnt lgkmcnt(0)" ::: "memory");                         \
    __builtin_amdgcn_s_barrier();                                              \
    asm volatile("" ::: "memory");                                             \
  }

#pragma unroll 1
  for (int t = 0; t < Ln; t += 4) {
    PHASE(0)
    PHASE(1)
    PHASE(2)
    PHASE(3)
  }
#undef PHASE
#undef SEQ_PF

  // ---- MFMA epilogue: out = h_final @ W_out^T + b_out; h_final in hbB[0] ----
  bf16x8 hz[4];
  const unsigned char* zb0 = hbB[0] + l15 * 256;
#pragma unroll
  for (int kt = 0; kt < 4; ++kt)
    hz[kt] = *(const bf16x8*)(zb0 + ((64 * kt + 16 * lg) ^ swz));
#pragma unroll
  for (int m = 0; m < 2; ++m) {
    const int v = 16 * (2 * w + m) + l15;
    const float* wor = W_out + (size_t)v * En + lg * 8;
    const float bo = b_out[v];
    f32x4 oa = {bo, bo, bo, bo};
#pragma unroll
    for (int kt = 0; kt < 4; ++kt) {
      float tmp[8];
      const float* p = wor + kt * 32;
#pragma unroll
      for (int i = 0; i < 8; ++i) tmp[i] = p[i];
      oa = MFMA(hz[kt], pack8(tmp), oa, 0, 0, 0);
    }
#pragma unroll
    for (int i = 0; i < 4; ++i)
      out[(size_t)(r0 + 4 * lg + i) * Vn + v] = oa[i];
  }
}

// ---------------- fallback path (round-4 kernel, known-correct) ----------------

__global__ void rnn_setup(const float* __restrict__ W_in, const float* __restrict__ b_in,
                          const float* __restrict__ W_h, const float* __restrict__ b_h,
                          float* __restrict__ ws) {
  const int j = blockIdx.x;
  const int k = threadIdx.x;
  const float* whr = W_h + j * (2 * En);
  float s;
  if (k < Vn) {
    s = 0.f;
#pragma unroll 8
    for (int e = 0; e < En; ++e) s = fmaf(W_in[e * Vn + k], whr[e], s);
  } else {
    s = whr[Vn + k];
  }
  ws[j * Kc + k] = s;
  if (k == 0) {
    float b = b_h[j];
    for (int e = 0; e < En; ++e) b = fmaf(b_in[e], whr[e], b);
    ws[En * Kc + j] = b;
  }
}

__global__ __launch_bounds__(256, 1) void rnn_mfma(
    const float* __restrict__ seq, const float* __restrict__ W_in,
    const float* __restrict__ b_in, const float* __restrict__ W_h,
    const float* __restrict__ b_h, const float* __restrict__ W_out,
    const float* __restrict__ b_out, float* __restrict__ out,
    const float* __restrict__ ws, int use_ws) {
  __shared__ __align__(16) unsigned short hb[2][16][HP];

  const int tid = threadIdx.x;
  const int w   = tid >> 6;
  const int l   = tid & 63;
  const int l15 = l & 15;
  const int lg  = l >> 4;
  const int r0  = blockIdx.x * 16;

  bf16x8 Bw[2][6];
  float bc[2];
  if (use_ws) {
#pragma unroll
    for (int n = 0; n < 2; ++n) {
      const int j = 32 * w + 16 * n + l15;
#pragma unroll
      for (int kt = 0; kt < 6; ++kt) {
        const float* p = ws + j * Kc + kt * 32 + lg * 8;
        float v[8];
#pragma unroll
        for (int i = 0; i < 8; ++i) v[i] = p[i];
        Bw[n][kt] = pack8(v);
      }
      bc[n] = ws[En * Kc + j];
    }
  } else {
#pragma unroll
    for (int n = 0; n < 2; ++n) {
      const int j = 32 * w + 16 * n + l15;
      const float* whr = W_h + j * (2 * En);
      float b = b_h[j];
      for (int e = 0; e < En; ++e) b = fmaf(b_in[e], whr[e], b);
      bc[n] = b;
#pragma unroll
      for (int kt = 0; kt < 6; ++kt) {
        float v[8];
#pragma unroll
        for (int i = 0; i < 8; ++i) {
          const int k = kt * 32 + lg * 8 + i;
          if (k < Vn) {
            float s = 0.f;
            for (int e = 0; e < En; ++e) s = fmaf(W_in[e * Vn + k], whr[e], s);
            v[i] = s;
          } else {
            v[i] = whr[Vn + k];
          }
        }
        Bw[n][kt] = pack8(v);
      }
    }
  }

  for (int i = tid; i < 2 * 16 * HP; i += 256) ((unsigned short*)hb)[i] = 0;

  const float* sq = seq + ((size_t)(r0 + l15) * Ln) * Vn + lg * 8;
  f32x4 sbuf[4][4];

#define SEQ_PF(BI, T)                                                 \
  { const int tp = ((T) < Ln) ? (T) : (Ln - 1);                       \
    const f32x4* p0 = (const f32x4*)(sq + (size_t)tp * Vn);           \
    const f32x4* p1 = (const f32x4*)(sq + (size_t)tp * Vn + 32);      \
    sbuf[BI][0] = p0[0]; sbuf[BI][1] = p0[1];                         \
    sbuf[BI][2] = p1[0]; sbuf[BI][3] = p1[1]; }

  SEQ_PF(0, 0)
  SEQ_PF(1, 1)
  SEQ_PF(2, 2)
  __syncthreads();

#define PHASE(P)                                                              \
  {                                                                           \
    const int cb = (P) & 1, nb = cb ^ 1;                                      \
    const bf16x8 h0 = *(const bf16x8*)&hb[cb][l15][lg * 8];                   \
    const bf16x8 h1 = *(const bf16x8*)&hb[cb][l15][32 + lg * 8];              \
    const bf16x8 h2 = *(const bf16x8*)&hb[cb][l15][64 + lg * 8];              \
    const bf16x8 h3 = *(const bf16x8*)&hb[cb][l15][96 + lg * 8];              \
    SEQ_PF(((P) + 3) & 3, t + (P) + 3);                                       \
    float v0[8], v1[8];                                                       \
    _Pragma("unroll") for (int i = 0; i < 4; ++i) {                           \
      v0[i] = sbuf[(P)][0][i]; v0[4 + i] = sbuf[(P)][1][i];                   \
      v1[i] = sbuf[(P)][2][i]; v1[4 + i] = sbuf[(P)][3][i];                   \
    }                                                                         \
    const bf16x8 a0 = pack8(v0), a1 = pack8(v1);                              \
    f32x4 p0a = {bc[0], bc[0], bc[0], bc[0]};                                 \
    f32x4 p1a = {bc[1], bc[1], bc[1], bc[1]};                                 \
    f32x4 q0a = {0.f, 0.f, 0.f, 0.f}, q1a = {0.f, 0.f, 0.f, 0.f};             \
    p0a = MFMA(a0, Bw[0][0], p0a, 0, 0, 0);                                   \
    p1a = MFMA(a0, Bw[1][0], p1a, 0, 0, 0);                                   \
    p0a = MFMA(a1, Bw[0][1], p0a, 0, 0, 0);                                   \
    p1a = MFMA(a1, Bw[1][1], p1a, 0, 0, 0);                                   \
    p0a = MFMA(h0, Bw[0][2], p0a, 0, 0, 0);                                   \
    p1a = MFMA(h0, Bw[1][2], p1a, 0, 0, 0);                                   \
    q0a = MFMA(h2, Bw[0][4], q0a, 0, 0, 0);                                   \
    q1a = MFMA(h2, Bw[1][4], q1a, 0, 0, 0);                                   \
    p0a = MFMA(h1, Bw[0][3], p0a, 0, 0, 0);                                   \
    p1a = MFMA(h1, Bw[1][3], p1a, 0, 0, 0);                                   \
    q0a = MFMA(h3, Bw[0][5], q0a, 0, 0, 0);                                   \
    q1a = MFMA(h3, Bw[1][5], q1a, 0, 0, 0);                                   \
    const int j0 = 32 * w + l15, j1 = j0 + 16, rr = 4 * lg;                   \
    _Pragma("unroll") for (int i = 0; i < 4; ++i) {                           \
      hb[nb][rr + i][j0] = (unsigned short)f2b(fmaxf(p0a[i] + q0a[i], 0.f));  \
      hb[nb][rr + i][j1] = (unsigned short)f2b(fmaxf(p1a[i] + q1a[i], 0.f));  \
    }                                                                         \
    asm volatile("s_waitcnt lgkmcnt(0)" ::: "memory");                        \
    __builtin_amdgcn_s_barrier();                                             \
    asm volatile("" ::: "memory");                                            \
  }

#pragma unroll 1
  for (int t = 0; t < Ln; t += 4) {
    PHASE(0)
    PHASE(1)
    PHASE(2)
    PHASE(3)
  }
#undef PHASE
#undef SEQ_PF

  const int orow = tid >> 4;
  const int oc   = (tid & 15) * 4;
  float o0 = b_out[oc], o1 = b_out[oc + 1], o2 = b_out[oc + 2], o3 = b_out[oc + 3];
  const float* w0 = W_out + (size_t)(oc + 0) * En;
  const float* w1 = W_out + (size_t)(oc + 1) * En;
  const float* w2 = W_out + (size_t)(oc + 2) * En;
  const float* w3 = W_out + (size_t)(oc + 3) * En;
#pragma unroll 8
  for (int k = 0; k < En; ++k) {
    const float hv = b2f(hb[0][orow][k]);
    o0 = fmaf(hv, w0[k], o0);
    o1 = fmaf(hv, w1[k], o1);
    o2 = fmaf(hv, w2[k], o2);
    o3 = fmaf(hv, w3[k], o3);
  }
  *(float4*)&out[(size_t)(r0 + orow) * Vn + oc] = make_float4(o0, o1, o2, o3);
}

extern "C" void kernel_launch(void* const* d_in, const int* in_sizes, int n_in,
                              void* d_out, int out_size, void* d_ws, size_t ws_size,
                              hipStream_t stream) {
  const float* seq   = (const float*)d_in[0];
  const float* W_in  = (const float*)d_in[1];
  const float* b_in  = (const float*)d_in[2];
  const float* W_h   = (const float*)d_in[3];
  const float* b_h   = (const float*)d_in[4];
  const float* W_out = (const float*)d_in[5];
  const float* b_out = (const float*)d_in[6];
  float* out = (float*)d_out;

  if (ws_size >= FAST_WS) {
    unsigned short* seqb  = (unsigned short*)d_ws;
    unsigned short* wallb = (unsigned short*)((char*)d_ws + SEQB_BYTES);
    float* bc = (float*)((char*)d_ws + SEQB_BYTES + WALLB_BYTES);
    seq_cvt<<<2048, 256, 0, stream>>>(seq, seqb);
    rnn_setup_bf<<<En, Kc, 0, stream>>>(W_in, b_in, W_h, b_h, wallb, bc);
    rnn_fast2<<<Bn / 16, 128, 0, stream>>>(seqb, wallb, bc, W_out, b_out, out);
  } else if (ws_size >= (size_t)WS_FLOATS * sizeof(float)) {
    float* ws = (float*)d_ws;
    rnn_setup<<<En, Kc, 0, stream>>>(W_in, b_in, W_h, b_h, ws);
    rnn_mfma<<<Bn / 16, 256, 0, stream>>>(seq, W_in, b_in, W_h, b_h, W_out, b_out,
                                          out, ws, 1);
  } else {
    rnn_mfma<<<Bn / 16, 256, 0, stream>>>(seq, W_in, b_in, W_h, b_h, W_out, b_out,
                                          out, (const float*)nullptr, 0);
  }
}